// Round 12
// baseline (499.669 us; speedup 1.0000x reference)
//
#include <hip/hip_runtime.h>

#define NUM_USER 100000
#define NUM_ITEM 50000
#define NNODE 150000
#define EMBED_DIM 64
#define NNZ_CNT 5000000
#define BATCH 4096

#define BROWS 256
#define NBUCK ((NNODE + BROWS - 1) / BROWS)       // 586
#define NBLK 512
#define CHUNK4 9768                                // per-block edges, multiple of 8
#define COLMASK 0x3FFFF                            // 18 bits, col < 262144
#define RLSHIFT 18                                 // rl in bits 18..25 of grouped.x
#define VSHIFT 18                                  // val14 in bits 18..31 of packed csr
#define VSCALE (1.0f / 16384.0f)

__device__ __forceinline__ unsigned short f2bf(float f) {
    unsigned b = __float_as_uint(f);
    return (unsigned short)((b + 0x7FFFu + ((b >> 16) & 1u)) >> 16);  // RNE
}
__device__ __forceinline__ float bf2f(unsigned short u) {
    return __uint_as_float((unsigned)u << 16);
}

// ---------- CSR build: per-block hist -> 2-level scan -> scatter -> bucket sort ----------

// Per-block LDS histogram; 4 consecutive edges/thread (int4 loads, 4-deep ILP).
__global__ __launch_bounds__(1024) void bhist_local(const int* __restrict__ row,
                                                    int* __restrict__ histT) {
    __shared__ int lh[NBUCK];
    for (int i = threadIdx.x; i < NBUCK; i += blockDim.x) lh[i] = 0;
    __syncthreads();
    const int lo = blockIdx.x * CHUNK4;
    const int hi = min(lo + CHUNK4, NNZ_CNT);
    for (int base = lo; base < hi; base += 4096) {
        const int e0 = base + (int)threadIdx.x * 4;
        if (e0 + 4 <= hi) {
            const int4 r4 = *(const int4*)&row[e0];
            atomicAdd(&lh[r4.x >> 8], 1);
            atomicAdd(&lh[r4.y >> 8], 1);
            atomicAdd(&lh[r4.z >> 8], 1);
            atomicAdd(&lh[r4.w >> 8], 1);
        } else if (e0 < hi) {
            for (int e = e0; e < hi; ++e) atomicAdd(&lh[row[e] >> 8], 1);
        }
    }
    __syncthreads();
    for (int i = threadIdx.x; i < NBUCK; i += blockDim.x)
        histT[i * NBLK + blockIdx.x] = lh[i];
}

__global__ __launch_bounds__(512) void scanA(int* __restrict__ histT,
                                             int* __restrict__ btot) {
    const int g = (int)((blockIdx.x * blockDim.x + threadIdx.x) >> 6);
    const int lane = threadIdx.x & 63;
    if (g >= NBUCK) return;
    const int base = g * NBLK + lane * 8;
    int v[8];
    int s = 0;
    #pragma unroll
    for (int u = 0; u < 8; ++u) { v[u] = histT[base + u]; s += v[u]; }
    int pre = s;
    #pragma unroll
    for (int off = 1; off < 64; off <<= 1) {
        int t = __shfl_up(pre, off, 64);
        if (lane >= off) pre += t;
    }
    int excl = pre - s;
    #pragma unroll
    for (int u = 0; u < 8; ++u) { const int w = v[u]; histT[base + u] = excl; excl += w; }
    if (lane == 63) btot[g] = pre;
}

__global__ __launch_bounds__(1024) void scanB(const int* __restrict__ btot,
                                              int* __restrict__ bptr) {
    __shared__ int sums[1024];
    const int t = threadIdx.x;
    const int s = (t < NBUCK) ? btot[t] : 0;
    sums[t] = s;
    __syncthreads();
    for (int off = 1; off < 1024; off <<= 1) {
        int v = (t >= off) ? sums[t - off] : 0;
        __syncthreads();
        sums[t] += v;
        __syncthreads();
    }
    if (t < NBUCK) bptr[t] = sums[t] - s;
    if (t == 0) bptr[NBUCK] = NNZ_CNT;
}

// Scatter edges into bucket-grouped order; 4 consecutive edges/thread.
__global__ __launch_bounds__(1024) void bscatter2(const float* __restrict__ vals,
                                                  const int* __restrict__ row,
                                                  const int* __restrict__ col,
                                                  const int* __restrict__ histT,
                                                  const int* __restrict__ bptr,
                                                  int2* __restrict__ grouped) {
    __shared__ int lh[NBUCK];
    const int b = blockIdx.x;
    for (int i = threadIdx.x; i < NBUCK; i += blockDim.x)
        lh[i] = bptr[i] + histT[i * NBLK + b];
    __syncthreads();
    const int lo = b * CHUNK4;
    const int hi = min(lo + CHUNK4, NNZ_CNT);
    for (int base = lo; base < hi; base += 4096) {
        const int e0 = base + (int)threadIdx.x * 4;
        if (e0 + 4 <= hi) {
            const int4   r4 = *(const int4*)&row[e0];
            const int4   c4 = *(const int4*)&col[e0];
            const float4 v4 = *(const float4*)&vals[e0];
            const int p0 = atomicAdd(&lh[r4.x >> 8], 1);
            const int p1 = atomicAdd(&lh[r4.y >> 8], 1);
            const int p2 = atomicAdd(&lh[r4.z >> 8], 1);
            const int p3 = atomicAdd(&lh[r4.w >> 8], 1);
            grouped[p0] = make_int2(c4.x | ((r4.x & 255) << RLSHIFT), __float_as_int(v4.x));
            grouped[p1] = make_int2(c4.y | ((r4.y & 255) << RLSHIFT), __float_as_int(v4.y));
            grouped[p2] = make_int2(c4.z | ((r4.z & 255) << RLSHIFT), __float_as_int(v4.z));
            grouped[p3] = make_int2(c4.w | ((r4.w & 255) << RLSHIFT), __float_as_int(v4.w));
        } else if (e0 < hi) {
            for (int e = e0; e < hi; ++e) {
                const int r = row[e];
                const int pos = atomicAdd(&lh[r >> 8], 1);
                grouped[pos] = make_int2(col[e] | ((r & 255) << RLSHIFT), __float_as_int(vals[e]));
            }
        }
    }
}

// One WG per bucket: LDS 256-bin hist + scan -> row_ptr + contiguous PACKED csr.
// 4-deep strided ILP on both grouped passes.
__global__ __launch_bounds__(512) void bucket_sort(const int* __restrict__ bptr,
                                                   const int2* __restrict__ grouped,
                                                   unsigned* __restrict__ csr,
                                                   int* __restrict__ row_ptr) {
    __shared__ int lh[BROWS];
    __shared__ int lbase[BROWS];
    const int b = blockIdx.x;
    const int bstart = bptr[b];
    const int bend   = bptr[b + 1];
    if (threadIdx.x < BROWS) lh[threadIdx.x] = 0;
    __syncthreads();
    int e = bstart + (int)threadIdx.x;
    for (; e + 1536 < bend; e += 2048) {
        const unsigned x0 = (unsigned)grouped[e].x;
        const unsigned x1 = (unsigned)grouped[e + 512].x;
        const unsigned x2 = (unsigned)grouped[e + 1024].x;
        const unsigned x3 = (unsigned)grouped[e + 1536].x;
        atomicAdd(&lh[x0 >> RLSHIFT], 1);
        atomicAdd(&lh[x1 >> RLSHIFT], 1);
        atomicAdd(&lh[x2 >> RLSHIFT], 1);
        atomicAdd(&lh[x3 >> RLSHIFT], 1);
    }
    for (; e < bend; e += 512)
        atomicAdd(&lh[((unsigned)grouped[e].x) >> RLSHIFT], 1);
    __syncthreads();
    if (threadIdx.x == 0) {
        int run = 0;
        for (int i = 0; i < BROWS; ++i) { const int c = lh[i]; lbase[i] = run; run += c; }
    }
    __syncthreads();
    const int node = b * BROWS + (int)threadIdx.x;
    if (threadIdx.x < BROWS && node < NNODE) row_ptr[node] = bstart + lbase[threadIdx.x];
    if (threadIdx.x < BROWS) lh[threadIdx.x] = lbase[threadIdx.x];
    __syncthreads();
    auto emit = [&](int2 rec) {
        const int rl = ((unsigned)rec.x) >> RLSHIFT;
        const int pos = bstart + atomicAdd(&lh[rl], 1);
        unsigned u = (unsigned)(__int_as_float(rec.y) * 16384.0f + 0.5f);
        if (u > 16383u) u = 16383u;
        csr[pos] = (u << VSHIFT) | ((unsigned)rec.x & COLMASK);
    };
    e = bstart + (int)threadIdx.x;
    for (; e + 1536 < bend; e += 2048) {
        const int2 r0 = grouped[e];
        const int2 r1 = grouped[e + 512];
        const int2 r2 = grouped[e + 1024];
        const int2 r3 = grouped[e + 1536];
        emit(r0); emit(r1); emit(r2); emit(r3);
    }
    for (; e < bend; e += 512) emit(grouped[e]);
}

__global__ void fix_tail(int* __restrict__ row_ptr) {
    row_ptr[NNODE] = NNZ_CNT;
}

// ---------- table concat -> bf16 ----------

__global__ void to_bf16(const float4* __restrict__ ut, const float4* __restrict__ it,
                        ushort4* __restrict__ xbf) {
    const int nu4 = NUM_USER * EMBED_DIM / 4;
    const int nt4 = NNODE * EMBED_DIM / 4;
    int i = blockIdx.x * blockDim.x + threadIdx.x;
    const int stride = gridDim.x * blockDim.x;
    for (; i < nt4; i += stride) {
        const float4 v = (i < nu4) ? ut[i] : it[i - nu4];
        ushort4 o;
        o.x = f2bf(v.x); o.y = f2bf(v.y); o.z = f2bf(v.z); o.w = f2bf(v.w);
        xbf[i] = o;
    }
}

// ---------- pull-mode SpMM (bf16 in / bf16 out), packed 4B CSR, pair-gather ----------
// One wave per row. Lane = (half, channel-pair): half=lane>>5 picks the edge of
// a pair, c2=lane&31 picks 2 bf16 channels loaded as one dword. One gather
// instruction covers TWO edges (same cache lines as before -> half the vmem
// instructions). acc is float2; cross-half combine via shfl_xor(32).

__global__ __launch_bounds__(256) void spmm_pull(const int* __restrict__ row_ptr,
                          const unsigned* __restrict__ csr,
                          const unsigned short* __restrict__ x,
                          unsigned short* __restrict__ y) {
    const int wave = (int)((blockIdx.x * blockDim.x + threadIdx.x) >> 6);
    const int lane = threadIdx.x & 63;
    if (wave >= NNODE) return;
    const int half = lane >> 5;
    const int c2   = lane & 31;
    const int start = __builtin_amdgcn_readfirstlane(row_ptr[wave]);
    const int end   = __builtin_amdgcn_readfirstlane(row_ptr[wave + 1]);
    float ax = 0.f, ay = 0.f;
    int j = start;
    for (; j + 16 <= end; j += 16) {
        unsigned ee[16];
        #pragma unroll
        for (int u = 0; u < 16; ++u) __builtin_memcpy(&ee[u], &csr[j + u], 4); // s_load x16
        unsigned w[8]; float vv[8];
        #pragma unroll
        for (int p = 0; p < 8; ++p) {
            const unsigned e = half ? ee[2 * p + 1] : ee[2 * p];   // cndmask
            w[p] = *(const unsigned*)((const char*)x +
                     (size_t)(e & COLMASK) * 128 + (size_t)c2 * 4); // 2 edges / instr
            vv[p] = (float)(e >> VSHIFT);
        }
        #pragma unroll
        for (int p = 0; p < 8; ++p) {
            ax += vv[p] * __uint_as_float(w[p] << 16);
            ay += vv[p] * __uint_as_float(w[p] & 0xFFFF0000u);
        }
    }
    const int rem = end - j;
    if (rem > 8) {                                  // masked 8-pair tail
        #pragma unroll
        for (int p = 0; p < 8; ++p) {
            const int j0 = j + 2 * p + half;
            const int idx = (j0 < end) ? j0 : end - 1;
            unsigned e; __builtin_memcpy(&e, &csr[idx], 4);
            const float v = (j0 < end) ? (float)(e >> VSHIFT) : 0.f;
            const unsigned w0 = *(const unsigned*)((const char*)x +
                     (size_t)(e & COLMASK) * 128 + (size_t)c2 * 4);
            ax += v * __uint_as_float(w0 << 16);
            ay += v * __uint_as_float(w0 & 0xFFFF0000u);
        }
    } else if (rem > 0) {                           // masked 4-pair tail
        #pragma unroll
        for (int p = 0; p < 4; ++p) {
            const int j0 = j + 2 * p + half;
            const int idx = (j0 < end) ? j0 : end - 1;
            unsigned e; __builtin_memcpy(&e, &csr[idx], 4);
            const float v = (j0 < end) ? (float)(e >> VSHIFT) : 0.f;
            const unsigned w0 = *(const unsigned*)((const char*)x +
                     (size_t)(e & COLMASK) * 128 + (size_t)c2 * 4);
            ax += v * __uint_as_float(w0 << 16);
            ay += v * __uint_as_float(w0 & 0xFFFF0000u);
        }
    }
    ax += __shfl_xor(ax, 32, 64);
    ay += __shfl_xor(ay, 32, 64);
    if (half == 0) {
        const unsigned lo = f2bf(ax * VSCALE);
        const unsigned hi = f2bf(ay * VSCALE);
        ((unsigned*)y)[(size_t)wave * 32 + c2] = (hi << 16) | lo;   // 128B/row, coalesced
    }
}

// Layer-3 restricted pull for the 8192 batch rows only (r11-proven 16-deep form).
__global__ __launch_bounds__(256) void batch_pull(const int* __restrict__ row_ptr,
                           const unsigned* __restrict__ csr,
                           const unsigned short* __restrict__ x,
                           const int* __restrict__ users,
                           const int* __restrict__ items,
                           float* __restrict__ uacc,
                           float* __restrict__ iacc) {
    const int g = (int)((blockIdx.x * blockDim.x + threadIdx.x) >> 6);
    const int lane = threadIdx.x & 63;
    if (g >= 2 * BATCH) return;
    const bool is_item = g >= BATCH;
    const int b = is_item ? g - BATCH : g;
    const int node = is_item ? items[b] + NUM_USER : users[b];
    const int start = __builtin_amdgcn_readfirstlane(row_ptr[node]);
    const int end   = __builtin_amdgcn_readfirstlane(row_ptr[node + 1]);
    float acc = 0.f;
    int j = start;
    for (; j + 16 <= end; j += 16) {
        unsigned ee[16]; float xv[16];
        #pragma unroll
        for (int u = 0; u < 16; ++u) {
            __builtin_memcpy(&ee[u], &csr[j + u], 4);
            xv[u] = bf2f(x[(size_t)(ee[u] & COLMASK) * EMBED_DIM + lane]);
        }
        #pragma unroll
        for (int u = 0; u < 16; ++u) acc += (float)(ee[u] >> VSHIFT) * xv[u];
    }
    const int rem = end - j;
    if (rem > 8) {
        float vv[16], xv[16];
        #pragma unroll
        for (int u = 0; u < 16; ++u) {
            const int jj = j + u;
            const int idx = (jj < end) ? jj : end - 1;
            unsigned e; __builtin_memcpy(&e, &csr[idx], 4);
            vv[u] = (jj < end) ? (float)(e >> VSHIFT) : 0.f;
            xv[u] = bf2f(x[(size_t)(e & COLMASK) * EMBED_DIM + lane]);
        }
        #pragma unroll
        for (int u = 0; u < 16; ++u) acc += vv[u] * xv[u];
    } else if (rem > 0) {
        float vv[8], xv[8];
        #pragma unroll
        for (int u = 0; u < 8; ++u) {
            const int jj = j + u;
            const int idx = (jj < end) ? jj : end - 1;
            unsigned e; __builtin_memcpy(&e, &csr[idx], 4);
            vv[u] = (jj < end) ? (float)(e >> VSHIFT) : 0.f;
            xv[u] = bf2f(x[(size_t)(e & COLMASK) * EMBED_DIM + lane]);
        }
        #pragma unroll
        for (int u = 0; u < 8; ++u) acc += vv[u] * xv[u];
    }
    float* dst = is_item ? iacc : uacc;
    dst[(size_t)b * EMBED_DIM + lane] += acc * VSCALE;
}

// ---------- accumulators / scoring ----------

__global__ void init_acc(const float* __restrict__ user_table,
                         const float* __restrict__ item_table,
                         const int* __restrict__ users,
                         const int* __restrict__ items,
                         float* __restrict__ uacc,
                         float* __restrict__ iacc) {
    const int tid = blockIdx.x * blockDim.x + threadIdx.x;
    const int b = tid >> 6;
    const int k = tid & 63;
    uacc[tid] = user_table[(size_t)users[b] * EMBED_DIM + k];
    iacc[tid] = item_table[(size_t)items[b] * EMBED_DIM + k];
}

__global__ void gather_add(const unsigned short* __restrict__ src,
                           const int* __restrict__ users,
                           const int* __restrict__ items,
                           float* __restrict__ uacc,
                           float* __restrict__ iacc) {
    const int tid = blockIdx.x * blockDim.x + threadIdx.x;
    const int b = tid >> 6;
    const int k = tid & 63;
    uacc[tid] += bf2f(src[(size_t)users[b] * EMBED_DIM + k]);
    iacc[tid] += bf2f(src[((size_t)items[b] + NUM_USER) * EMBED_DIM + k]);
}

__global__ void score_kernel(const float* __restrict__ uacc,
                             const float* __restrict__ iacc,
                             float* __restrict__ out) {
    const int tid = blockIdx.x * blockDim.x + threadIdx.x;
    const int b = tid >> 6;
    const int k = tid & 63;
    float p = uacc[tid] * iacc[tid];
    #pragma unroll
    for (int off = 32; off > 0; off >>= 1) p += __shfl_down(p, off, 64);
    if (k == 0) out[b] = p * (1.0f / 16.0f);
}

// ---------- launch ----------

extern "C" void kernel_launch(void* const* d_in, const int* in_sizes, int n_in,
                              void* d_out, int out_size, void* d_ws, size_t ws_size,
                              hipStream_t stream) {
    const float* vals       = (const float*)d_in[0];
    const float* user_table = (const float*)d_in[1];
    const float* item_table = (const float*)d_in[2];
    const int*   row        = (const int*)d_in[3];
    const int*   col        = (const int*)d_in[4];
    const int*   users      = (const int*)d_in[5];
    const int*   items      = (const int*)d_in[6];
    float* out = (float*)d_out;

    char* ws = (char*)d_ws;
    size_t off = 0;
    auto alloc = [&](size_t bytes) { char* p = ws + off; off += (bytes + 255) & ~(size_t)255; return p; };
    const size_t NBH = (size_t)NNODE * EMBED_DIM * sizeof(unsigned short); // 19.2 MB
    unsigned short* xbf  = (unsigned short*)alloc(NBH);
    unsigned short* bufA = (unsigned short*)alloc(NBH);
    int2*  grouped = (int2*)alloc((size_t)NNZ_CNT * sizeof(int2));      // 40 MB (bufB aliases)
    unsigned* csr  = (unsigned*)alloc((size_t)NNZ_CNT * sizeof(unsigned)); // 20 MB packed
    int*   row_ptr = (int*)alloc((size_t)(NNODE + 1) * sizeof(int));
    int*   bptr    = (int*)alloc((size_t)(NBUCK + 1) * sizeof(int));
    int*   btot    = (int*)alloc((size_t)NBUCK * sizeof(int));
    int*   histT   = (int*)alloc((size_t)NBUCK * NBLK * sizeof(int));   // 1.2 MB
    float* uacc    = (float*)alloc((size_t)BATCH * EMBED_DIM * sizeof(float));
    float* iacc    = (float*)alloc((size_t)BATCH * EMBED_DIM * sizeof(float));

    // CSR build
    bhist_local<<<NBLK, 1024, 0, stream>>>(row, histT);
    scanA<<<(NBUCK * 64 + 511) / 512, 512, 0, stream>>>(histT, btot);
    scanB<<<1, 1024, 0, stream>>>(btot, bptr);
    bscatter2<<<NBLK, 1024, 0, stream>>>(vals, row, col, histT, bptr, grouped);
    bucket_sort<<<NBUCK, 512, 0, stream>>>(bptr, grouped, csr, row_ptr);
    fix_tail<<<1, 1, 0, stream>>>(row_ptr);

    // concat tables -> bf16
    to_bf16<<<2048, 256, 0, stream>>>((const float4*)user_table,
                                      (const float4*)item_table, (ushort4*)xbf);

    // hop 0
    init_acc<<<(BATCH * EMBED_DIM) / 256, 256, 0, stream>>>(user_table, item_table,
                                                            users, items, uacc, iacc);
    // hop 1 (full N)
    spmm_pull<<<(NNODE + 3) / 4, 256, 0, stream>>>(row_ptr, csr, xbf, bufA);
    gather_add<<<(BATCH * EMBED_DIM) / 256, 256, 0, stream>>>(bufA, users, items, uacc, iacc);
    // hop 2 (full N); output aliases `grouped` (dead after bucket_sort)
    unsigned short* bufB = (unsigned short*)grouped;
    spmm_pull<<<(NNODE + 3) / 4, 256, 0, stream>>>(row_ptr, csr, bufA, bufB);
    gather_add<<<(BATCH * EMBED_DIM) / 256, 256, 0, stream>>>(bufB, users, items, uacc, iacc);
    // hop 3 (restricted to the 8192 batch rows)
    batch_pull<<<(2 * BATCH * 64) / 256, 256, 0, stream>>>(row_ptr, csr, bufB,
                                                           users, items, uacc, iacc);
    // scores
    score_kernel<<<(BATCH * EMBED_DIM) / 256, 256, 0, stream>>>(uacc, iacc, out);
}

// Round 13
// 286.475 us; speedup vs baseline: 1.7442x; 1.7442x over previous
//
#include <hip/hip_runtime.h>

#define NUM_USER 100000
#define NUM_ITEM 50000
#define NNODE 150000
#define EMBED_DIM 64
#define NNZ_CNT 5000000
#define BATCH 4096

#define BROWS 256
#define NBUCK ((NNODE + BROWS - 1) / BROWS)       // 586
#define NBLK 512
#define CHUNK4 9768                                // per-block edges, multiple of 8
#define COLMASK 0x3FFFF                            // 18 bits, col < 262144
#define RLSHIFT 18                                 // rl in bits 18..25 of grouped.x
#define VSHIFT 18                                  // val14 in bits 18..31 of packed csr
#define VSCALE (1.0f / 16384.0f)

__device__ __forceinline__ unsigned short f2bf(float f) {
    unsigned b = __float_as_uint(f);
    return (unsigned short)((b + 0x7FFFu + ((b >> 16) & 1u)) >> 16);  // RNE
}
__device__ __forceinline__ float bf2f(unsigned short u) {
    return __uint_as_float((unsigned)u << 16);
}

// ---------- CSR build: per-block hist -> 2-level scan -> scatter -> bucket sort ----------

// Per-block LDS histogram; 4 consecutive edges/thread (int4 loads, 4-deep ILP).
__global__ __launch_bounds__(1024) void bhist_local(const int* __restrict__ row,
                                                    int* __restrict__ histT) {
    __shared__ int lh[NBUCK];
    for (int i = threadIdx.x; i < NBUCK; i += blockDim.x) lh[i] = 0;
    __syncthreads();
    const int lo = blockIdx.x * CHUNK4;
    const int hi = min(lo + CHUNK4, NNZ_CNT);
    for (int base = lo; base < hi; base += 4096) {
        const int e0 = base + (int)threadIdx.x * 4;
        if (e0 + 4 <= hi) {
            const int4 r4 = *(const int4*)&row[e0];
            atomicAdd(&lh[r4.x >> 8], 1);
            atomicAdd(&lh[r4.y >> 8], 1);
            atomicAdd(&lh[r4.z >> 8], 1);
            atomicAdd(&lh[r4.w >> 8], 1);
        } else if (e0 < hi) {
            for (int e = e0; e < hi; ++e) atomicAdd(&lh[row[e] >> 8], 1);
        }
    }
    __syncthreads();
    for (int i = threadIdx.x; i < NBUCK; i += blockDim.x)
        histT[i * NBLK + blockIdx.x] = lh[i];
}

__global__ __launch_bounds__(512) void scanA(int* __restrict__ histT,
                                             int* __restrict__ btot) {
    const int g = (int)((blockIdx.x * blockDim.x + threadIdx.x) >> 6);
    const int lane = threadIdx.x & 63;
    if (g >= NBUCK) return;
    const int base = g * NBLK + lane * 8;
    int v[8];
    int s = 0;
    #pragma unroll
    for (int u = 0; u < 8; ++u) { v[u] = histT[base + u]; s += v[u]; }
    int pre = s;
    #pragma unroll
    for (int off = 1; off < 64; off <<= 1) {
        int t = __shfl_up(pre, off, 64);
        if (lane >= off) pre += t;
    }
    int excl = pre - s;
    #pragma unroll
    for (int u = 0; u < 8; ++u) { const int w = v[u]; histT[base + u] = excl; excl += w; }
    if (lane == 63) btot[g] = pre;
}

__global__ __launch_bounds__(1024) void scanB(const int* __restrict__ btot,
                                              int* __restrict__ bptr) {
    __shared__ int sums[1024];
    const int t = threadIdx.x;
    const int s = (t < NBUCK) ? btot[t] : 0;
    sums[t] = s;
    __syncthreads();
    for (int off = 1; off < 1024; off <<= 1) {
        int v = (t >= off) ? sums[t - off] : 0;
        __syncthreads();
        sums[t] += v;
        __syncthreads();
    }
    if (t < NBUCK) bptr[t] = sums[t] - s;
    if (t == 0) bptr[NBUCK] = NNZ_CNT;
}

// Scatter edges into bucket-grouped order; 4 consecutive edges/thread.
__global__ __launch_bounds__(1024) void bscatter2(const float* __restrict__ vals,
                                                  const int* __restrict__ row,
                                                  const int* __restrict__ col,
                                                  const int* __restrict__ histT,
                                                  const int* __restrict__ bptr,
                                                  int2* __restrict__ grouped) {
    __shared__ int lh[NBUCK];
    const int b = blockIdx.x;
    for (int i = threadIdx.x; i < NBUCK; i += blockDim.x)
        lh[i] = bptr[i] + histT[i * NBLK + b];
    __syncthreads();
    const int lo = b * CHUNK4;
    const int hi = min(lo + CHUNK4, NNZ_CNT);
    for (int base = lo; base < hi; base += 4096) {
        const int e0 = base + (int)threadIdx.x * 4;
        if (e0 + 4 <= hi) {
            const int4   r4 = *(const int4*)&row[e0];
            const int4   c4 = *(const int4*)&col[e0];
            const float4 v4 = *(const float4*)&vals[e0];
            const int p0 = atomicAdd(&lh[r4.x >> 8], 1);
            const int p1 = atomicAdd(&lh[r4.y >> 8], 1);
            const int p2 = atomicAdd(&lh[r4.z >> 8], 1);
            const int p3 = atomicAdd(&lh[r4.w >> 8], 1);
            grouped[p0] = make_int2(c4.x | ((r4.x & 255) << RLSHIFT), __float_as_int(v4.x));
            grouped[p1] = make_int2(c4.y | ((r4.y & 255) << RLSHIFT), __float_as_int(v4.y));
            grouped[p2] = make_int2(c4.z | ((r4.z & 255) << RLSHIFT), __float_as_int(v4.z));
            grouped[p3] = make_int2(c4.w | ((r4.w & 255) << RLSHIFT), __float_as_int(v4.w));
        } else if (e0 < hi) {
            for (int e = e0; e < hi; ++e) {
                const int r = row[e];
                const int pos = atomicAdd(&lh[r >> 8], 1);
                grouped[pos] = make_int2(col[e] | ((r & 255) << RLSHIFT), __float_as_int(vals[e]));
            }
        }
    }
}

// One WG per bucket: LDS 256-bin hist + scan -> row_ptr + contiguous PACKED csr.
// 4-deep strided ILP on both grouped passes.
__global__ __launch_bounds__(512) void bucket_sort(const int* __restrict__ bptr,
                                                   const int2* __restrict__ grouped,
                                                   unsigned* __restrict__ csr,
                                                   int* __restrict__ row_ptr) {
    __shared__ int lh[BROWS];
    __shared__ int lbase[BROWS];
    const int b = blockIdx.x;
    const int bstart = bptr[b];
    const int bend   = bptr[b + 1];
    if (threadIdx.x < BROWS) lh[threadIdx.x] = 0;
    __syncthreads();
    int e = bstart + (int)threadIdx.x;
    for (; e + 1536 < bend; e += 2048) {
        const unsigned x0 = (unsigned)grouped[e].x;
        const unsigned x1 = (unsigned)grouped[e + 512].x;
        const unsigned x2 = (unsigned)grouped[e + 1024].x;
        const unsigned x3 = (unsigned)grouped[e + 1536].x;
        atomicAdd(&lh[x0 >> RLSHIFT], 1);
        atomicAdd(&lh[x1 >> RLSHIFT], 1);
        atomicAdd(&lh[x2 >> RLSHIFT], 1);
        atomicAdd(&lh[x3 >> RLSHIFT], 1);
    }
    for (; e < bend; e += 512)
        atomicAdd(&lh[((unsigned)grouped[e].x) >> RLSHIFT], 1);
    __syncthreads();
    if (threadIdx.x == 0) {
        int run = 0;
        for (int i = 0; i < BROWS; ++i) { const int c = lh[i]; lbase[i] = run; run += c; }
    }
    __syncthreads();
    const int node = b * BROWS + (int)threadIdx.x;
    if (threadIdx.x < BROWS && node < NNODE) row_ptr[node] = bstart + lbase[threadIdx.x];
    if (threadIdx.x < BROWS) lh[threadIdx.x] = lbase[threadIdx.x];
    __syncthreads();
    auto emit = [&](int2 rec) {
        const int rl = ((unsigned)rec.x) >> RLSHIFT;
        const int pos = bstart + atomicAdd(&lh[rl], 1);
        unsigned u = (unsigned)(__int_as_float(rec.y) * 16384.0f + 0.5f);
        if (u > 16383u) u = 16383u;
        csr[pos] = (u << VSHIFT) | ((unsigned)rec.x & COLMASK);
    };
    e = bstart + (int)threadIdx.x;
    for (; e + 1536 < bend; e += 2048) {
        const int2 r0 = grouped[e];
        const int2 r1 = grouped[e + 512];
        const int2 r2 = grouped[e + 1024];
        const int2 r3 = grouped[e + 1536];
        emit(r0); emit(r1); emit(r2); emit(r3);
    }
    for (; e < bend; e += 512) emit(grouped[e]);
}

__global__ void fix_tail(int* __restrict__ row_ptr) {
    row_ptr[NNODE] = NNZ_CNT;
}

// ---------- table concat -> bf16 ----------

__global__ void to_bf16(const float4* __restrict__ ut, const float4* __restrict__ it,
                        ushort4* __restrict__ xbf) {
    const int nu4 = NUM_USER * EMBED_DIM / 4;
    const int nt4 = NNODE * EMBED_DIM / 4;
    int i = blockIdx.x * blockDim.x + threadIdx.x;
    const int stride = gridDim.x * blockDim.x;
    for (; i < nt4; i += stride) {
        const float4 v = (i < nu4) ? ut[i] : it[i - nu4];
        ushort4 o;
        o.x = f2bf(v.x); o.y = f2bf(v.y); o.z = f2bf(v.z); o.w = f2bf(v.w);
        xbf[i] = o;
    }
}

// ---------- pull-mode SpMM (bf16 in / bf16 out), packed 4B CSR ----------
// r11-PROVEN form: one wave per row, lane = channel; wave-uniform scalar CSR
// loads at constant offsets interleaved with their gather use (keeps staging
// in registers -- do NOT split into load-all/use-all phases, r12 lesson);
// masked-16/masked-8 wave-uniform tails, vals zeroed on waste slots.

__global__ __launch_bounds__(256) void spmm_pull(const int* __restrict__ row_ptr,
                          const unsigned* __restrict__ csr,
                          const unsigned short* __restrict__ x,
                          unsigned short* __restrict__ y) {
    const int wave = (int)((blockIdx.x * blockDim.x + threadIdx.x) >> 6);
    const int lane = threadIdx.x & 63;
    if (wave >= NNODE) return;
    const int start = __builtin_amdgcn_readfirstlane(row_ptr[wave]);
    const int end   = __builtin_amdgcn_readfirstlane(row_ptr[wave + 1]);
    float acc = 0.f;
    int j = start;
    for (; j + 16 <= end; j += 16) {
        unsigned ee[16]; float xv[16];
        #pragma unroll
        for (int u = 0; u < 16; ++u) {
            __builtin_memcpy(&ee[u], &csr[j + u], 4);            // s_load, const offset
            xv[u] = bf2f(x[(size_t)(ee[u] & COLMASK) * EMBED_DIM + lane]);
        }
        #pragma unroll
        for (int u = 0; u < 16; ++u) acc += (float)(ee[u] >> VSHIFT) * xv[u];
    }
    const int rem = end - j;
    if (rem > 8) {                                 // masked-16 (wave-uniform branch)
        float vv[16], xv[16];
        #pragma unroll
        for (int u = 0; u < 16; ++u) {
            const int jj = j + u;
            const int idx = (jj < end) ? jj : end - 1;
            unsigned e; __builtin_memcpy(&e, &csr[idx], 4);
            vv[u] = (jj < end) ? (float)(e >> VSHIFT) : 0.f;
            xv[u] = bf2f(x[(size_t)(e & COLMASK) * EMBED_DIM + lane]);
        }
        #pragma unroll
        for (int u = 0; u < 16; ++u) acc += vv[u] * xv[u];
    } else if (rem > 0) {                          // masked-8
        float vv[8], xv[8];
        #pragma unroll
        for (int u = 0; u < 8; ++u) {
            const int jj = j + u;
            const int idx = (jj < end) ? jj : end - 1;
            unsigned e; __builtin_memcpy(&e, &csr[idx], 4);
            vv[u] = (jj < end) ? (float)(e >> VSHIFT) : 0.f;
            xv[u] = bf2f(x[(size_t)(e & COLMASK) * EMBED_DIM + lane]);
        }
        #pragma unroll
        for (int u = 0; u < 8; ++u) acc += vv[u] * xv[u];
    }
    y[(size_t)wave * EMBED_DIM + lane] = f2bf(acc * VSCALE);
}

// Layer-3 restricted pull for the 8192 batch rows only (same pattern).
__global__ __launch_bounds__(256) void batch_pull(const int* __restrict__ row_ptr,
                           const unsigned* __restrict__ csr,
                           const unsigned short* __restrict__ x,
                           const int* __restrict__ users,
                           const int* __restrict__ items,
                           float* __restrict__ uacc,
                           float* __restrict__ iacc) {
    const int g = (int)((blockIdx.x * blockDim.x + threadIdx.x) >> 6);
    const int lane = threadIdx.x & 63;
    if (g >= 2 * BATCH) return;
    const bool is_item = g >= BATCH;
    const int b = is_item ? g - BATCH : g;
    const int node = is_item ? items[b] + NUM_USER : users[b];
    const int start = __builtin_amdgcn_readfirstlane(row_ptr[node]);
    const int end   = __builtin_amdgcn_readfirstlane(row_ptr[node + 1]);
    float acc = 0.f;
    int j = start;
    for (; j + 16 <= end; j += 16) {
        unsigned ee[16]; float xv[16];
        #pragma unroll
        for (int u = 0; u < 16; ++u) {
            __builtin_memcpy(&ee[u], &csr[j + u], 4);
            xv[u] = bf2f(x[(size_t)(ee[u] & COLMASK) * EMBED_DIM + lane]);
        }
        #pragma unroll
        for (int u = 0; u < 16; ++u) acc += (float)(ee[u] >> VSHIFT) * xv[u];
    }
    const int rem = end - j;
    if (rem > 8) {
        float vv[16], xv[16];
        #pragma unroll
        for (int u = 0; u < 16; ++u) {
            const int jj = j + u;
            const int idx = (jj < end) ? jj : end - 1;
            unsigned e; __builtin_memcpy(&e, &csr[idx], 4);
            vv[u] = (jj < end) ? (float)(e >> VSHIFT) : 0.f;
            xv[u] = bf2f(x[(size_t)(e & COLMASK) * EMBED_DIM + lane]);
        }
        #pragma unroll
        for (int u = 0; u < 16; ++u) acc += vv[u] * xv[u];
    } else if (rem > 0) {
        float vv[8], xv[8];
        #pragma unroll
        for (int u = 0; u < 8; ++u) {
            const int jj = j + u;
            const int idx = (jj < end) ? jj : end - 1;
            unsigned e; __builtin_memcpy(&e, &csr[idx], 4);
            vv[u] = (jj < end) ? (float)(e >> VSHIFT) : 0.f;
            xv[u] = bf2f(x[(size_t)(e & COLMASK) * EMBED_DIM + lane]);
        }
        #pragma unroll
        for (int u = 0; u < 8; ++u) acc += vv[u] * xv[u];
    }
    float* dst = is_item ? iacc : uacc;
    dst[(size_t)b * EMBED_DIM + lane] += acc * VSCALE;
}

// ---------- accumulators / scoring ----------

__global__ void init_acc(const float* __restrict__ user_table,
                         const float* __restrict__ item_table,
                         const int* __restrict__ users,
                         const int* __restrict__ items,
                         float* __restrict__ uacc,
                         float* __restrict__ iacc) {
    const int tid = blockIdx.x * blockDim.x + threadIdx.x;
    const int b = tid >> 6;
    const int k = tid & 63;
    uacc[tid] = user_table[(size_t)users[b] * EMBED_DIM + k];
    iacc[tid] = item_table[(size_t)items[b] * EMBED_DIM + k];
}

__global__ void gather_add(const unsigned short* __restrict__ src,
                           const int* __restrict__ users,
                           const int* __restrict__ items,
                           float* __restrict__ uacc,
                           float* __restrict__ iacc) {
    const int tid = blockIdx.x * blockDim.x + threadIdx.x;
    const int b = tid >> 6;
    const int k = tid & 63;
    uacc[tid] += bf2f(src[(size_t)users[b] * EMBED_DIM + k]);
    iacc[tid] += bf2f(src[((size_t)items[b] + NUM_USER) * EMBED_DIM + k]);
}

__global__ void score_kernel(const float* __restrict__ uacc,
                             const float* __restrict__ iacc,
                             float* __restrict__ out) {
    const int tid = blockIdx.x * blockDim.x + threadIdx.x;
    const int b = tid >> 6;
    const int k = tid & 63;
    float p = uacc[tid] * iacc[tid];
    #pragma unroll
    for (int off = 32; off > 0; off >>= 1) p += __shfl_down(p, off, 64);
    if (k == 0) out[b] = p * (1.0f / 16.0f);
}

// ---------- launch ----------

extern "C" void kernel_launch(void* const* d_in, const int* in_sizes, int n_in,
                              void* d_out, int out_size, void* d_ws, size_t ws_size,
                              hipStream_t stream) {
    const float* vals       = (const float*)d_in[0];
    const float* user_table = (const float*)d_in[1];
    const float* item_table = (const float*)d_in[2];
    const int*   row        = (const int*)d_in[3];
    const int*   col        = (const int*)d_in[4];
    const int*   users      = (const int*)d_in[5];
    const int*   items      = (const int*)d_in[6];
    float* out = (float*)d_out;

    char* ws = (char*)d_ws;
    size_t off = 0;
    auto alloc = [&](size_t bytes) { char* p = ws + off; off += (bytes + 255) & ~(size_t)255; return p; };
    const size_t NBH = (size_t)NNODE * EMBED_DIM * sizeof(unsigned short); // 19.2 MB
    unsigned short* xbf  = (unsigned short*)alloc(NBH);
    unsigned short* bufA = (unsigned short*)alloc(NBH);
    int2*  grouped = (int2*)alloc((size_t)NNZ_CNT * sizeof(int2));      // 40 MB (bufB aliases)
    unsigned* csr  = (unsigned*)alloc((size_t)NNZ_CNT * sizeof(unsigned)); // 20 MB packed
    int*   row_ptr = (int*)alloc((size_t)(NNODE + 1) * sizeof(int));
    int*   bptr    = (int*)alloc((size_t)(NBUCK + 1) * sizeof(int));
    int*   btot    = (int*)alloc((size_t)NBUCK * sizeof(int));
    int*   histT   = (int*)alloc((size_t)NBUCK * NBLK * sizeof(int));   // 1.2 MB
    float* uacc    = (float*)alloc((size_t)BATCH * EMBED_DIM * sizeof(float));
    float* iacc    = (float*)alloc((size_t)BATCH * EMBED_DIM * sizeof(float));

    // CSR build
    bhist_local<<<NBLK, 1024, 0, stream>>>(row, histT);
    scanA<<<(NBUCK * 64 + 511) / 512, 512, 0, stream>>>(histT, btot);
    scanB<<<1, 1024, 0, stream>>>(btot, bptr);
    bscatter2<<<NBLK, 1024, 0, stream>>>(vals, row, col, histT, bptr, grouped);
    bucket_sort<<<NBUCK, 512, 0, stream>>>(bptr, grouped, csr, row_ptr);
    fix_tail<<<1, 1, 0, stream>>>(row_ptr);

    // concat tables -> bf16
    to_bf16<<<2048, 256, 0, stream>>>((const float4*)user_table,
                                      (const float4*)item_table, (ushort4*)xbf);

    // hop 0
    init_acc<<<(BATCH * EMBED_DIM) / 256, 256, 0, stream>>>(user_table, item_table,
                                                            users, items, uacc, iacc);
    // hop 1 (full N)
    spmm_pull<<<(NNODE + 3) / 4, 256, 0, stream>>>(row_ptr, csr, xbf, bufA);
    gather_add<<<(BATCH * EMBED_DIM) / 256, 256, 0, stream>>>(bufA, users, items, uacc, iacc);
    // hop 2 (full N); output aliases `grouped` (dead after bucket_sort)
    unsigned short* bufB = (unsigned short*)grouped;
    spmm_pull<<<(NNODE + 3) / 4, 256, 0, stream>>>(row_ptr, csr, bufA, bufB);
    gather_add<<<(BATCH * EMBED_DIM) / 256, 256, 0, stream>>>(bufB, users, items, uacc, iacc);
    // hop 3 (restricted to the 8192 batch rows)
    batch_pull<<<(2 * BATCH * 64) / 256, 256, 0, stream>>>(row_ptr, csr, bufB,
                                                           users, items, uacc, iacc);
    // scores
    score_kernel<<<(BATCH * EMBED_DIM) / 256, 256, 0, stream>>>(uacc, iacc, out);
}